// Round 16
// baseline (192.387 us; speedup 1.0000x reference)
//
#include <hip/hip_runtime.h>
#include <math.h>

#define BB   2
#define SS   1024
#define HH   768
#define DD   24
#define HIDD 96
#define VINN 2304   // 3*H
#define VHIDD 768
#define NRR  2048   // BB*SS

typedef __attribute__((ext_vector_type(8))) short short8;
typedef __attribute__((ext_vector_type(4))) float floatx4;

static __device__ inline unsigned short f2bf(float x) {
    unsigned int u = __float_as_uint(x);
    u = (u + 0x7FFFu + ((u >> 16) & 1u)) >> 16;
    return (unsigned short)u;
}
// RNE packed f32 -> 2x bf16 in ONE VALU op (gfx950 v_cvt_pk_bf16_f32; no builtin)
static __device__ inline unsigned int pack2(float a, float b) {
    unsigned int r;
    asm("v_cvt_pk_bf16_f32 %0, %1, %2" : "=v"(r) : "v"(a), "v"(b));
    return r;
}

// async global -> LDS, 16 B per lane; LDS dest = wave-uniform base + lane*16
static __device__ inline void gl16(const unsigned short* g, unsigned short* l) {
    __builtin_amdgcn_global_load_lds(
        (const __attribute__((address_space(1))) unsigned int*)g,
        (__attribute__((address_space(3))) unsigned int*)l,
        16, 0, 0);
}

// ---------------- Kernel 0: Z projections via MFMA (64 blocks) -------------
__global__ __launch_bounds__(256) void k_zproj(
    const float* __restrict__ Hj, const float* __restrict__ Hi,
    const float* __restrict__ Wpj, const float* __restrict__ Wpi,
    unsigned* __restrict__ Zjp, unsigned* __restrict__ Zip)
{
    __shared__ __align__(16) unsigned short sAz[64][72];
    __shared__ __align__(16) unsigned short sBTz[32][72];
    int tid = threadIdx.x;
    int w = tid >> 6, lane = tid & 63;
    int quad = lane >> 4, col = lane & 15;
    int m0 = blockIdx.x * 64;
    bool isJ = (m0 < NRR);
    const float* src = isJ ? Hj : Hi;
    const float* Wp  = isJ ? Wpj : Wpi;
    unsigned* Zp     = isJ ? Zjp : Zip;
    int rowbase = isJ ? m0 : (m0 - NRR);

    floatx4 acc[2];
    acc[0] = (floatx4){0.f,0.f,0.f,0.f};
    acc[1] = (floatx4){0.f,0.f,0.f,0.f};

    for (int kb = 0; kb < HH; kb += 64) {
        #pragma unroll
        for (int i = 0; i < 4; ++i) {
            int f4 = tid + i*256;
            int r = f4 >> 4, c4 = f4 & 15;
            float4 v = *(const float4*)(src + (size_t)(rowbase + r)*HH + kb + c4*4);
            uint2 pkt; pkt.x = pack2(v.x, v.y); pkt.y = pack2(v.z, v.w);
            *(uint2*)&sAz[r][c4*4] = pkt;
        }
        {
            const float* wsrc = Wp + (size_t)kb*DD;
            #pragma unroll
            for (int i = 0; i < 6; ++i) {
                int idx = tid + i*256;
                int k = idx / DD, n = idx % DD;
                sBTz[n][k] = f2bf(wsrc[idx]);
            }
        }
        __syncthreads();
        #pragma unroll
        for (int kt = 0; kt < 2; ++kt) {
            short8 av = *(const short8*)&sAz[w*16 + col][kt*32 + quad*8];
            #pragma unroll
            for (int nt = 0; nt < 2; ++nt) {
                short8 bv = *(const short8*)&sBTz[nt*16 + col][kt*32 + quad*8];
                acc[nt] = __builtin_amdgcn_mfma_f32_16x16x32_bf16(av, bv, acc[nt], 0, 0, 0);
            }
        }
        __syncthreads();
    }
    #pragma unroll
    for (int nt = 0; nt < 2; ++nt) {
        #pragma unroll
        for (int r = 0; r < 4; ++r) {
            float v = acc[nt][r];
            float vn = __shfl_xor(v, 1, 64);
            int n = nt*16 + col;
            if (!(col & 1) && n < DD) {
                int m = w*16 + quad*4 + r;
                Zp[(size_t)(rowbase + m)*12 + (n >> 1)] = pack2(v, vn);
            }
        }
    }
}

// ---------------- Kernel 2: MFMA logits + softmax -> probs (bf16) ----------
// 256 threads / 4 waves; TC=64, 16 chunks. KEY: the chunk loop is fully
// WAVE-LOCAL — wave wv packs A-rows [wv*16,wv*16+16) (t_loc=tid>>2) and its
// MFMA consumes exactly those rows (arow=wv*16+col); sLog slices are also
// wave-disjoint. So NO __syncthreads in the loop: waves free-run, each wave's
// VMEM/MFMA phases overlap other waves' pack VALU. One barrier before softmax.
// blocks 0..2047: attention rows.  blocks 2048..: f32->bf16 transpose-convert.
#define LSTR 72
#define TC 64
#define NC (SS/TC)   // 16
__global__ __launch_bounds__(256) void k_attn(
    const unsigned* __restrict__ Zjp, const unsigned* __restrict__ Zip,
    const float* __restrict__ W1, const float* __restrict__ b1,
    const float* __restrict__ W2,
    const float* __restrict__ mask, unsigned short* __restrict__ probs,
    const float* __restrict__ Hi, const float* __restrict__ Wv1,
    const float* __restrict__ Wv2,
    unsigned short* __restrict__ Wv1T, unsigned short* __restrict__ Wv2T,
    unsigned short* __restrict__ HiT)
{
    int tid = threadIdx.x;
    __shared__ __align__(16) unsigned short sAB[2][TC*LSTR]; // B-build flat, then A dbuf
    __shared__ __align__(16) float sLog[SS];
    __shared__ unsigned sZjp[12];
    __shared__ float sW2[HIDD];
    __shared__ float sRed[4];
    unsigned short* sABf = &sAB[0][0];   // flat view (rows 0..127)

    if (blockIdx.x >= NRR) {
        // ---------------- tconv segment ----------------
        int b2 = blockIdx.x - NRR;
        const float* in; unsigned short* out; int R, C, r0, c0;
        if (b2 < 1728) {                 // Wv1T: [2304][768] -> [768][2304]
            in = Wv1; out = Wv1T; R = VINN; C = VHIDD;
            c0 = (b2 % 24) * 32; r0 = (b2 / 24) * 32;
        } else if (b2 < 2304) {          // Wv2T: [768][768] -> [768][768]
            int t = b2 - 1728;
            in = Wv2; out = Wv2T; R = VHIDD; C = HH;
            c0 = (t % 24) * 32; r0 = (t / 24) * 32;
        } else {                          // HiT: per batch [1024][768] -> [768][1024]
            int t = b2 - 2304;
            int z = t / 768; t %= 768;
            in = Hi + (size_t)z*SS*HH; out = HiT + (size_t)z*HH*SS;
            R = SS; C = HH;
            c0 = (t % 24) * 32; r0 = (t / 24) * 32;
        }
        float* tile = (float*)sABf;      // 32x33 floats = 4224 B, fits in sAB
        int tc = tid & 31, tr = tid >> 5;
        #pragma unroll
        for (int i = 0; i < 4; ++i)
            tile[(tr + i*8)*33 + tc] = in[(size_t)(r0 + tr + i*8)*C + c0 + tc];
        __syncthreads();
        #pragma unroll
        for (int i = 0; i < 4; ++i)
            out[(size_t)(c0 + tr + i*8)*R + r0 + tc] = f2bf(tile[tc*33 + tr + i*8]);
        return;
    }

    // ---------------- attention row ----------------
    int row = blockIdx.x;       // b*S + s
    int b = row >> 10;
    int lane = tid & 63, wv = tid >> 6;
    int quad = lane >> 4, col = lane & 15;

    if (tid < 12) sZjp[tid] = Zjp[(size_t)row*12 + tid];
    if (tid < HIDD) sW2[tid] = W2[tid];
    __syncthreads();

    // ---- build B flat (rows h = 0..95, k = 0..63) ----
    if (tid < HIDD) {
        int h = tid;
        float zj[24];
        #pragma unroll
        for (int u = 0; u < 12; ++u) {
            unsigned z = sZjp[u];
            zj[2*u]   = __uint_as_float(z << 16);
            zj[2*u+1] = __uint_as_float(z & 0xffff0000u);
        }
        float tj = b1[h];
        #pragma unroll
        for (int d = 0; d < DD; ++d) tj = fmaf(zj[d], W1[d*HIDD + h], tj);
        unsigned short* rowp = sABf + h*LSTR;
        #pragma unroll
        for (int d = 0; d < DD; ++d)
            rowp[d] = f2bf(fmaf(zj[d], W1[(48+d)*HIDD + h], W1[(24+d)*HIDD + h]));
        #pragma unroll
        for (int d = 0; d < DD; ++d)
            rowp[24+d] = f2bf(W1[(72+d)*HIDD + h]);
        rowp[48] = f2bf(tj);
        #pragma unroll
        for (int k = 49; k < 64; ++k) rowp[k] = 0;
    }
    __syncthreads();

    // hoist B fragments (h-side, MFMA A-operand) + per-lane w2 coeffs
    short8 bfr[6][2];
    #pragma unroll
    for (int nf = 0; nf < 6; ++nf)
        #pragma unroll
        for (int kt = 0; kt < 2; ++kt)
            bfr[nf][kt] = *(const short8*)&sABf[(nf*16 + col)*LSTR + kt*32 + quad*8];
    float4 w2q[6];
    #pragma unroll
    for (int nf = 0; nf < 6; ++nf)
        w2q[nf] = *(const float4*)&sW2[nf*16 + quad*4];
    __syncthreads();   // sAB now reused as A double-buffer (wave-local slices)

    // constant region k=48..63, both parities — WAVE-LOCAL rows only
    if (lane < 32) {
        int bf = lane >> 4, r = wv*16 + (lane & 15);
        unsigned short* rowp = &sAB[bf][r*LSTR];
        uint4 w0; w0.x = 0x3F80u; w0.y = 0; w0.z = 0; w0.w = 0;
        *(uint4*)&rowp[48] = w0;
        uint4 zz; zz.x = 0; zz.y = 0; zz.z = 0; zz.w = 0;
        *(uint4*)&rowp[56] = zz;
    }
    // no barrier: each wave reads only its own slice below

    int t_loc = tid >> 2, ss = tid & 3;
    const unsigned* zbase = Zip + (size_t)(b << 10) * 12;

    // hoist Zj unpack (chunk-invariant) for this thread's 3 q-uints
    float zalo[3], zahi[3];
    #pragma unroll
    for (int u = 0; u < 3; ++u) {
        unsigned za = sZjp[3*ss + u];
        zalo[u] = __uint_as_float(za << 16);
        zahi[u] = __uint_as_float(za & 0xffff0000u);
    }

    // issue: launch chunk's global loads into registers (no use)
    auto issue = [&](int chunk, uint4 &cp, unsigned (&mz)[3]) {
        int t = chunk*TC + t_loc;
        const unsigned* zr = zbase + (size_t)t*12;
        if (ss < 3) cp = *(const uint4*)(zr + 4*ss);
        #pragma unroll
        for (int u = 0; u < 3; ++u) mz[u] = zr[3*ss + u];
    };
    // packw: pack-math + LDS writes from previously-loaded registers
    auto packw = [&](int bf, const uint4 &cp, const unsigned (&mz)[3]) {
        unsigned short* rowp = &sAB[bf][t_loc*LSTR];
        if (ss < 3) *(uint4*)&rowp[8*ss] = cp;
        #pragma unroll
        for (int u = 0; u < 3; ++u) {
            unsigned zb = mz[u];
            float blo = __uint_as_float(zb << 16);
            float bhi = __uint_as_float(zb & 0xffff0000u);
            float dlo = fabsf(zalo[u] - blo);
            float dhi = fabsf(zahi[u] - bhi);
            *(unsigned*)&rowp[24 + 6*ss + 2*u] = pack2(dlo, dhi);
        }
    };
    auto mfma_fold = [&](int chunk, int cur) {
        int arow = wv*16 + col;
        short8 av0 = *(const short8*)&sAB[cur][arow*LSTR + quad*8];
        short8 av1 = *(const short8*)&sAB[cur][arow*LSTR + 32 + quad*8];
        float s0 = 0.f;
        __builtin_amdgcn_s_setprio(1);
        #pragma unroll
        for (int hf = 0; hf < 6; ++hf) {
            floatx4 a0 = {0.f,0.f,0.f,0.f};
            a0 = __builtin_amdgcn_mfma_f32_16x16x32_bf16(bfr[hf][0], av0, a0, 0, 0, 0);
            a0 = __builtin_amdgcn_mfma_f32_16x16x32_bf16(bfr[hf][1], av1, a0, 0, 0, 0);
            float w2v[4] = {w2q[hf].x, w2q[hf].y, w2q[hf].z, w2q[hf].w};
            #pragma unroll
            for (int r = 0; r < 4; ++r)
                s0 = fmaf(fmaxf(a0[r], 0.f), w2v[r], s0);
        }
        __builtin_amdgcn_s_setprio(0);
        s0 += __shfl_xor(s0, 16, 64);
        s0 += __shfl_xor(s0, 32, 64);
        if (lane < 16)
            sLog[chunk*TC + wv*16 + lane] = s0;
    };

    // prologue: chunks 0 and 1 in flight in registers
    uint4 cpA, cpB; unsigned mzA[3], mzB[3];
    issue(0, cpA, mzA);
    issue(1, cpB, mzB);

    // barrier-free steady state: each wave free-runs its 16-row slices.
    // ds_write -> ds_read ordering within a wave is handled by lgkmcnt.
    #pragma unroll
    for (int cc = 0; cc < NC; cc += 2) {
        packw(0, cpA, mzA);                          // chunk cc -> parity 0
        if (cc + 2 < NC) issue(cc + 2, cpA, mzA);    // latency hides under mfma
        mfma_fold(cc, 0);
        packw(1, cpB, mzB);                          // chunk cc+1 -> parity 1
        if (cc + 3 < NC) issue(cc + 3, cpB, mzB);
        mfma_fold(cc + 1, 1);
    }
    __syncthreads();   // sLog complete across waves

    // ---- softmax ----
    float lv[4];
    #pragma unroll
    for (int i = 0; i < 4; ++i) {
        int t = tid + i*256;
        lv[i] = sLog[t] + (1.0f - mask[(size_t)(b<<10) + t]) * (-3.402823466e+38f);
    }
    float m = fmaxf(fmaxf(lv[0], lv[1]), fmaxf(lv[2], lv[3]));
    #pragma unroll
    for (int off = 32; off; off >>= 1) m = fmaxf(m, __shfl_down(m, off, 64));
    if (lane == 0) sRed[wv] = m;
    __syncthreads();
    float M = fmaxf(fmaxf(sRed[0], sRed[1]), fmaxf(sRed[2], sRed[3]));
    float e[4]; float ssum = 0.f;
    #pragma unroll
    for (int i = 0; i < 4; ++i) { e[i] = expf(lv[i] - M); ssum += e[i]; }
    #pragma unroll
    for (int off = 32; off; off >>= 1) ssum += __shfl_down(ssum, off, 64);
    __syncthreads();
    if (lane == 0) sRed[wv] = ssum;
    __syncthreads();
    float inv = 1.0f / (sRed[0] + sRed[1] + sRed[2] + sRed[3]);
    #pragma unroll
    for (int i = 0; i < 4; ++i)
        probs[(size_t)row*SS + tid + i*256] = f2bf(e[i] * inv);
}

// ---------------- Kernel 3: depth-2 pipelined GEMM, 64Mx32N ----------------
// R6's BK=64 loop exposed full load latency every step (the __syncthreads
// vmcnt(0) drain waits even for the JUST-issued prefetch — why R7's dbuf was
// null).  This version keeps the stage->barrier->4xMFMA->barrier shape but
// with 3 LDS buffers + raw s_barrier + COUNTED vmcnt (T4): tile t's loads
// issue at step t-2 and are waited with vmcnt(6)/(3)/(0) — never draining
// the in-flight prefetch.  sched_barrier(0) fences stop the scheduler from
// hoisting ds_reads across the barrier (rule #18 discipline).
// Buffer safety: stage(t+2) writes (t+2)%3 != t%3 read parity; overwrite of
// t%3 (stage t+3, step t+1) issues only after step t's post-MFMA barrier.
// MODE 0: msgin builder (ctx | hj | ctx*hj, bf16)
// MODE 1: Y1 = bf16(relu(acc + bias))
// MODE 2: out = f32(alpha*(acc + bias))
template<int MODE>
__global__ __launch_bounds__(256) void k_mgemm_nf(
    const unsigned short* __restrict__ A,
    const unsigned short* __restrict__ BT,
    const float* __restrict__ bias,
    const float* __restrict__ Hj,
    const float* __restrict__ alpha_p,
    void* __restrict__ Cout,
    int K, int bt_bstride)
{
    __shared__ __align__(16) unsigned short sA[3][64*64];   // 24 KB
    __shared__ __align__(16) unsigned short sB[3][32*64];   // 12 KB
    int tid = threadIdx.x;
    int w = tid >> 6, lane = tid & 63;
    int quad = lane >> 4, col = lane & 15;

    // T1 swizzle (measured neutral, kept): each XCD owns contiguous tiles.
    int nwgx = gridDim.x;
    int bid  = blockIdx.y * nwgx + blockIdx.x;
    int q    = (nwgx * gridDim.y) >> 3;            // nwg/8, exact (768/8=96)
    int swz  = (bid & 7) * q + (bid >> 3);
    int n0 = (swz % nwgx) * 32, m0 = (swz / nwgx) * 64;

    int nk = K >> 6;
    const unsigned short* Bb = BT + (size_t)(m0 >> 10) * bt_bstride;

    int srow = lane >> 3;
    int skc  = (lane & 7) * 8;

    floatx4 acc[2];
    acc[0] = (floatx4){0.f,0.f,0.f,0.f};
    acc[1] = (floatx4){0.f,0.f,0.f,0.f};

    auto stage = [&](int kb, int buf) {
        int kofs = kb*64;
        gl16(A  + (size_t)(m0 + w*16     + srow)*K + kofs + skc, &sA[buf][(w*16)*64]);
        gl16(A  + (size_t)(m0 + w*16 + 8 + srow)*K + kofs + skc, &sA[buf][(w*16 + 8)*64]);
        gl16(Bb + (size_t)(n0 + w*8      + srow)*K + kofs + skc, &sB[buf][(w*8)*64]);
    };

    stage(0, 0);
    if (nk > 1) stage(1, 1);

    int cur = 0;
    for (int kb = 0; kb < nk; ++kb) {
        if (kb + 2 < nk) {
            int nb = cur + 2; if (nb >= 3) nb -= 3;
            stage(kb + 2, nb);                       // depth-2 prefetch
            asm volatile("s_waitcnt vmcnt(6)" ::: "memory");  // tile kb done
        } else if (kb + 1 < nk) {
            asm volatile("s_waitcnt vmcnt(3)" ::: "memory");
        } else {
            asm volatile("s_waitcnt vmcnt(0)" ::: "memory");
        }
        __builtin_amdgcn_s_barrier();                // all waves: tile kb ready
        __builtin_amdgcn_sched_barrier(0);           // no ds_read hoist above
        #pragma unroll
        for (int kt = 0; kt < 2; ++kt) {
            short8 av = *(const short8*)&sA[cur][(w*16 + col)*64 + kt*32 + quad*8];
            #pragma unroll
            for (int nf = 0; nf < 2; ++nf) {
                short8 bv = *(const short8*)&sB[cur][(nf*16 + col)*64 + kt*32 + quad*8];
                acc[nf] = __builtin_amdgcn_mfma_f32_16x16x32_bf16(av, bv, acc[nf], 0, 0, 0);
            }
        }
        __builtin_amdgcn_sched_barrier(0);           // reads stay above barrier
        __builtin_amdgcn_s_barrier();                // all waves done reading cur
        __builtin_amdgcn_sched_barrier(0);           // next stage stays below
        cur = (cur + 1 == 3) ? 0 : cur + 1;
    }

    float alpha = (MODE == 2) ? alpha_p[0] : 1.0f;
    #pragma unroll
    for (int nf = 0; nf < 2; ++nf) {
        int n = n0 + nf*16 + col;
        #pragma unroll
        for (int r = 0; r < 4; ++r) {
            int m = w*16 + quad*4 + r;
            size_t g = (size_t)(m0 + m);
            float v = acc[nf][r];
            if (MODE == 0) {
                float hj = Hj[g*HH + n];
                unsigned short* msgin = (unsigned short*)Cout;
                msgin[g*VINN + n]        = f2bf(v);
                msgin[g*VINN + HH + n]   = f2bf(hj);
                msgin[g*VINN + 2*HH + n] = f2bf(v*hj);
            } else if (MODE == 1) {
                ((unsigned short*)Cout)[g*VHIDD + n] =
                    f2bf(fmaxf(v + bias[n], 0.f));
            } else {
                ((float*)Cout)[g*HH + n] = alpha*(v + bias[n]);
            }
        }
    }
}

extern "C" void kernel_launch(void* const* d_in, const int* in_sizes, int n_in,
                              void* d_out, int out_size, void* d_ws, size_t ws_size,
                              hipStream_t stream)
{
    const float* Hj   = (const float*)d_in[0];
    const float* Hi   = (const float*)d_in[1];
    const float* mask = (const float*)d_in[2];
    const float* Wpj  = (const float*)d_in[3];
    const float* Wpi  = (const float*)d_in[4];
    const float* W1   = (const float*)d_in[5];
    const float* b1   = (const float*)d_in[6];
    const float* W2   = (const float*)d_in[7];
    const float* Wv1  = (const float*)d_in[9];
    const float* bv1  = (const float*)d_in[10];
    const float* Wv2  = (const float*)d_in[11];
    const float* bv2  = (const float*)d_in[12];
    const float* alpha = (const float*)d_in[13];
    float* out = (float*)d_out;

    const int NR = NRR;                   // 2048
    char* p = (char*)d_ws;
    auto alloc = [&](size_t bytes) {
        char* r = p; p += (bytes + 255) & ~(size_t)255; return r;
    };
    unsigned* Zjp          = (unsigned*)alloc((size_t)NR*12*4);
    unsigned* Zip          = (unsigned*)alloc((size_t)NR*12*4);
    unsigned short* probsb = (unsigned short*)alloc((size_t)NR*SS*2);
    unsigned short* HiT    = (unsigned short*)alloc((size_t)BB*HH*SS*2);
    unsigned short* Wv1T   = (unsigned short*)alloc((size_t)VHIDD*VINN*2);
    unsigned short* Wv2T   = (unsigned short*)alloc((size_t)HH*VHIDD*2);
    unsigned short* msginb = (unsigned short*)alloc((size_t)NR*VINN*2);
    unsigned short* Y1b    = (unsigned short*)alloc((size_t)NR*VHIDD*2);

    // zproj only: 64 blocks (k_attn depends solely on this)
    k_zproj<<<2*NR/64, 256, 0, stream>>>(Hj, Hi, Wpj, Wpi, Zjp, Zip);

    // attn (2048 blocks) + tconv (3840 blocks) packed in one dispatch:
    // tconv outputs (HiT/Wv1T/Wv2T) are first consumed by the GEMMs below.
    k_attn<<<NR + 1728 + 576 + 1536, 256, 0, stream>>>(
        Zjp, Zip, W1, b1, W2, mask, probsb,
        Hi, Wv1, Wv2, Wv1T, Wv2T, HiT);

    // ctx GEMM: M=2048 (batch via bt stride), N=768, K=1024, no split,
    // fused msgin epilogue. 24 x 32 = 768 blocks.
    k_mgemm_nf<0><<<dim3(HH/32, NR/64), 256, 0, stream>>>(
        probsb, HiT, nullptr, Hj, alpha, msginb, SS, HH*SS);

    // MLP GEMM1: K=2304, no split, fused bias+relu epilogue. 768 blocks.
    k_mgemm_nf<1><<<dim3(VHIDD/32, NR/64), 256, 0, stream>>>(
        msginb, Wv1T, bv1, nullptr, alpha, Y1b, VINN, 0);

    // MLP GEMM2: K=768, no split, fused f32 epilogue. 768 blocks.
    k_mgemm_nf<2><<<dim3(HH/32, NR/64), 256, 0, stream>>>(
        Y1b, Wv2T, bv2, nullptr, alpha, out, VHIDD, 0);
}

// Round 18
// 185.597 us; speedup vs baseline: 1.0366x; 1.0366x over previous
//
#include <hip/hip_runtime.h>
#include <math.h>

#define BB   2
#define SS   1024
#define HH   768
#define DD   24
#define HIDD 96
#define VINN 2304   // 3*H
#define VHIDD 768
#define NRR  2048   // BB*SS

typedef __attribute__((ext_vector_type(8))) short short8;
typedef __attribute__((ext_vector_type(4))) float floatx4;

static __device__ inline unsigned short f2bf(float x) {
    unsigned int u = __float_as_uint(x);
    u = (u + 0x7FFFu + ((u >> 16) & 1u)) >> 16;
    return (unsigned short)u;
}
// RNE packed f32 -> 2x bf16 in ONE VALU op (gfx950 v_cvt_pk_bf16_f32; no builtin)
static __device__ inline unsigned int pack2(float a, float b) {
    unsigned int r;
    asm("v_cvt_pk_bf16_f32 %0, %1, %2" : "=v"(r) : "v"(a), "v"(b));
    return r;
}

// async global -> LDS, 16 B per lane; LDS dest = wave-uniform base + lane*16
static __device__ inline void gl16(const unsigned short* g, unsigned short* l) {
    __builtin_amdgcn_global_load_lds(
        (const __attribute__((address_space(1))) unsigned int*)g,
        (__attribute__((address_space(3))) unsigned int*)l,
        16, 0, 0);
}

// ---------------- Kernel 0: Z projections via MFMA (64 blocks) -------------
__global__ __launch_bounds__(256) void k_zproj(
    const float* __restrict__ Hj, const float* __restrict__ Hi,
    const float* __restrict__ Wpj, const float* __restrict__ Wpi,
    unsigned* __restrict__ Zjp, unsigned* __restrict__ Zip)
{
    __shared__ __align__(16) unsigned short sAz[64][72];
    __shared__ __align__(16) unsigned short sBTz[32][72];
    int tid = threadIdx.x;
    int w = tid >> 6, lane = tid & 63;
    int quad = lane >> 4, col = lane & 15;
    int m0 = blockIdx.x * 64;
    bool isJ = (m0 < NRR);
    const float* src = isJ ? Hj : Hi;
    const float* Wp  = isJ ? Wpj : Wpi;
    unsigned* Zp     = isJ ? Zjp : Zip;
    int rowbase = isJ ? m0 : (m0 - NRR);

    floatx4 acc[2];
    acc[0] = (floatx4){0.f,0.f,0.f,0.f};
    acc[1] = (floatx4){0.f,0.f,0.f,0.f};

    for (int kb = 0; kb < HH; kb += 64) {
        #pragma unroll
        for (int i = 0; i < 4; ++i) {
            int f4 = tid + i*256;
            int r = f4 >> 4, c4 = f4 & 15;
            float4 v = *(const float4*)(src + (size_t)(rowbase + r)*HH + kb + c4*4);
            uint2 pkt; pkt.x = pack2(v.x, v.y); pkt.y = pack2(v.z, v.w);
            *(uint2*)&sAz[r][c4*4] = pkt;
        }
        {
            const float* wsrc = Wp + (size_t)kb*DD;
            #pragma unroll
            for (int i = 0; i < 6; ++i) {
                int idx = tid + i*256;
                int k = idx / DD, n = idx % DD;
                sBTz[n][k] = f2bf(wsrc[idx]);
            }
        }
        __syncthreads();
        #pragma unroll
        for (int kt = 0; kt < 2; ++kt) {
            short8 av = *(const short8*)&sAz[w*16 + col][kt*32 + quad*8];
            #pragma unroll
            for (int nt = 0; nt < 2; ++nt) {
                short8 bv = *(const short8*)&sBTz[nt*16 + col][kt*32 + quad*8];
                acc[nt] = __builtin_amdgcn_mfma_f32_16x16x32_bf16(av, bv, acc[nt], 0, 0, 0);
            }
        }
        __syncthreads();
    }
    #pragma unroll
    for (int nt = 0; nt < 2; ++nt) {
        #pragma unroll
        for (int r = 0; r < 4; ++r) {
            float v = acc[nt][r];
            float vn = __shfl_xor(v, 1, 64);
            int n = nt*16 + col;
            if (!(col & 1) && n < DD) {
                int m = w*16 + quad*4 + r;
                Zp[(size_t)(rowbase + m)*12 + (n >> 1)] = pack2(v, vn);
            }
        }
    }
}

// ---------------- Kernel 2: MFMA logits + softmax -> probs (bf16) ----------
// 256 threads / 4 waves; TC=64, 16 chunks. KEY: the chunk loop is fully
// WAVE-LOCAL — wave wv packs A-rows [wv*16,wv*16+16) (t_loc=tid>>2) and its
// MFMA consumes exactly those rows (arow=wv*16+col); sLog slices are also
// wave-disjoint. So NO __syncthreads in the loop: waves free-run, each wave's
// VMEM/MFMA phases overlap other waves' pack VALU. One barrier before softmax.
// blocks 0..2047: attention rows.  blocks 2048..: f32->bf16 transpose-convert.
#define LSTR 72
#define TC 64
#define NC (SS/TC)   // 16
__global__ __launch_bounds__(256) void k_attn(
    const unsigned* __restrict__ Zjp, const unsigned* __restrict__ Zip,
    const float* __restrict__ W1, const float* __restrict__ b1,
    const float* __restrict__ W2,
    const float* __restrict__ mask, unsigned short* __restrict__ probs,
    const float* __restrict__ Hi, const float* __restrict__ Wv1,
    const float* __restrict__ Wv2,
    unsigned short* __restrict__ Wv1T, unsigned short* __restrict__ Wv2T,
    unsigned short* __restrict__ HiT)
{
    int tid = threadIdx.x;
    __shared__ __align__(16) unsigned short sAB[2][TC*LSTR]; // B-build flat, then A dbuf
    __shared__ __align__(16) float sLog[SS];
    __shared__ unsigned sZjp[12];
    __shared__ float sW2[HIDD];
    __shared__ float sRed[4];
    unsigned short* sABf = &sAB[0][0];   // flat view (rows 0..127)

    if (blockIdx.x >= NRR) {
        // ---------------- tconv segment ----------------
        int b2 = blockIdx.x - NRR;
        const float* in; unsigned short* out; int R, C, r0, c0;
        if (b2 < 1728) {                 // Wv1T: [2304][768] -> [768][2304]
            in = Wv1; out = Wv1T; R = VINN; C = VHIDD;
            c0 = (b2 % 24) * 32; r0 = (b2 / 24) * 32;
        } else if (b2 < 2304) {          // Wv2T: [768][768] -> [768][768]
            int t = b2 - 1728;
            in = Wv2; out = Wv2T; R = VHIDD; C = HH;
            c0 = (t % 24) * 32; r0 = (t / 24) * 32;
        } else {                          // HiT: per batch [1024][768] -> [768][1024]
            int t = b2 - 2304;
            int z = t / 768; t %= 768;
            in = Hi + (size_t)z*SS*HH; out = HiT + (size_t)z*HH*SS;
            R = SS; C = HH;
            c0 = (t % 24) * 32; r0 = (t / 24) * 32;
        }
        float* tile = (float*)sABf;      // 32x33 floats = 4224 B, fits in sAB
        int tc = tid & 31, tr = tid >> 5;
        #pragma unroll
        for (int i = 0; i < 4; ++i)
            tile[(tr + i*8)*33 + tc] = in[(size_t)(r0 + tr + i*8)*C + c0 + tc];
        __syncthreads();
        #pragma unroll
        for (int i = 0; i < 4; ++i)
            out[(size_t)(c0 + tr + i*8)*R + r0 + tc] = f2bf(tile[tc*33 + tr + i*8]);
        return;
    }

    // ---------------- attention row ----------------
    int row = blockIdx.x;       // b*S + s
    int b = row >> 10;
    int lane = tid & 63, wv = tid >> 6;
    int quad = lane >> 4, col = lane & 15;

    if (tid < 12) sZjp[tid] = Zjp[(size_t)row*12 + tid];
    if (tid < HIDD) sW2[tid] = W2[tid];
    __syncthreads();

    // ---- build B flat (rows h = 0..95, k = 0..63) ----
    if (tid < HIDD) {
        int h = tid;
        float zj[24];
        #pragma unroll
        for (int u = 0; u < 12; ++u) {
            unsigned z = sZjp[u];
            zj[2*u]   = __uint_as_float(z << 16);
            zj[2*u+1] = __uint_as_float(z & 0xffff0000u);
        }
        float tj = b1[h];
        #pragma unroll
        for (int d = 0; d < DD; ++d) tj = fmaf(zj[d], W1[d*HIDD + h], tj);
        unsigned short* rowp = sABf + h*LSTR;
        #pragma unroll
        for (int d = 0; d < DD; ++d)
            rowp[d] = f2bf(fmaf(zj[d], W1[(48+d)*HIDD + h], W1[(24+d)*HIDD + h]));
        #pragma unroll
        for (int d = 0; d < DD; ++d)
            rowp[24+d] = f2bf(W1[(72+d)*HIDD + h]);
        rowp[48] = f2bf(tj);
        #pragma unroll
        for (int k = 49; k < 64; ++k) rowp[k] = 0;
    }
    __syncthreads();

    // hoist B fragments (h-side, MFMA A-operand) + per-lane w2 coeffs
    short8 bfr[6][2];
    #pragma unroll
    for (int nf = 0; nf < 6; ++nf)
        #pragma unroll
        for (int kt = 0; kt < 2; ++kt)
            bfr[nf][kt] = *(const short8*)&sABf[(nf*16 + col)*LSTR + kt*32 + quad*8];
    float4 w2q[6];
    #pragma unroll
    for (int nf = 0; nf < 6; ++nf)
        w2q[nf] = *(const float4*)&sW2[nf*16 + quad*4];
    __syncthreads();   // sAB now reused as A double-buffer (wave-local slices)

    // constant region k=48..63, both parities — WAVE-LOCAL rows only
    if (lane < 32) {
        int bf = lane >> 4, r = wv*16 + (lane & 15);
        unsigned short* rowp = &sAB[bf][r*LSTR];
        uint4 w0; w0.x = 0x3F80u; w0.y = 0; w0.z = 0; w0.w = 0;
        *(uint4*)&rowp[48] = w0;
        uint4 zz; zz.x = 0; zz.y = 0; zz.z = 0; zz.w = 0;
        *(uint4*)&rowp[56] = zz;
    }
    // no barrier: each wave reads only its own slice below

    int t_loc = tid >> 2, ss = tid & 3;
    const unsigned* zbase = Zip + (size_t)(b << 10) * 12;

    // hoist Zj unpack (chunk-invariant) for this thread's 3 q-uints
    float zalo[3], zahi[3];
    #pragma unroll
    for (int u = 0; u < 3; ++u) {
        unsigned za = sZjp[3*ss + u];
        zalo[u] = __uint_as_float(za << 16);
        zahi[u] = __uint_as_float(za & 0xffff0000u);
    }

    // issue: launch chunk's global loads into registers (no use)
    auto issue = [&](int chunk, uint4 &cp, unsigned (&mz)[3]) {
        int t = chunk*TC + t_loc;
        const unsigned* zr = zbase + (size_t)t*12;
        if (ss < 3) cp = *(const uint4*)(zr + 4*ss);
        #pragma unroll
        for (int u = 0; u < 3; ++u) mz[u] = zr[3*ss + u];
    };
    // packw: pack-math + LDS writes from previously-loaded registers
    auto packw = [&](int bf, const uint4 &cp, const unsigned (&mz)[3]) {
        unsigned short* rowp = &sAB[bf][t_loc*LSTR];
        if (ss < 3) *(uint4*)&rowp[8*ss] = cp;
        #pragma unroll
        for (int u = 0; u < 3; ++u) {
            unsigned zb = mz[u];
            float blo = __uint_as_float(zb << 16);
            float bhi = __uint_as_float(zb & 0xffff0000u);
            float dlo = fabsf(zalo[u] - blo);
            float dhi = fabsf(zahi[u] - bhi);
            *(unsigned*)&rowp[24 + 6*ss + 2*u] = pack2(dlo, dhi);
        }
    };
    auto mfma_fold = [&](int chunk, int cur) {
        int arow = wv*16 + col;
        short8 av0 = *(const short8*)&sAB[cur][arow*LSTR + quad*8];
        short8 av1 = *(const short8*)&sAB[cur][arow*LSTR + 32 + quad*8];
        float s0 = 0.f;
        __builtin_amdgcn_s_setprio(1);
        #pragma unroll
        for (int hf = 0; hf < 6; ++hf) {
            floatx4 a0 = {0.f,0.f,0.f,0.f};
            a0 = __builtin_amdgcn_mfma_f32_16x16x32_bf16(bfr[hf][0], av0, a0, 0, 0, 0);
            a0 = __builtin_amdgcn_mfma_f32_16x16x32_bf16(bfr[hf][1], av1, a0, 0, 0, 0);
            float w2v[4] = {w2q[hf].x, w2q[hf].y, w2q[hf].z, w2q[hf].w};
            #pragma unroll
            for (int r = 0; r < 4; ++r)
                s0 = fmaf(fmaxf(a0[r], 0.f), w2v[r], s0);
        }
        __builtin_amdgcn_s_setprio(0);
        s0 += __shfl_xor(s0, 16, 64);
        s0 += __shfl_xor(s0, 32, 64);
        if (lane < 16)
            sLog[chunk*TC + wv*16 + lane] = s0;
    };

    // prologue: chunks 0 and 1 in flight in registers
    uint4 cpA, cpB; unsigned mzA[3], mzB[3];
    issue(0, cpA, mzA);
    issue(1, cpB, mzB);

    // barrier-free steady state: each wave free-runs its 16-row slices.
    // ds_write -> ds_read ordering within a wave is handled by lgkmcnt.
    #pragma unroll
    for (int cc = 0; cc < NC; cc += 2) {
        packw(0, cpA, mzA);                          // chunk cc -> parity 0
        if (cc + 2 < NC) issue(cc + 2, cpA, mzA);    // latency hides under mfma
        mfma_fold(cc, 0);
        packw(1, cpB, mzB);                          // chunk cc+1 -> parity 1
        if (cc + 3 < NC) issue(cc + 3, cpB, mzB);
        mfma_fold(cc + 1, 1);
    }
    __syncthreads();   // sLog complete across waves

    // ---- softmax ----
    float lv[4];
    #pragma unroll
    for (int i = 0; i < 4; ++i) {
        int t = tid + i*256;
        lv[i] = sLog[t] + (1.0f - mask[(size_t)(b<<10) + t]) * (-3.402823466e+38f);
    }
    float m = fmaxf(fmaxf(lv[0], lv[1]), fmaxf(lv[2], lv[3]));
    #pragma unroll
    for (int off = 32; off; off >>= 1) m = fmaxf(m, __shfl_down(m, off, 64));
    if (lane == 0) sRed[wv] = m;
    __syncthreads();
    float M = fmaxf(fmaxf(sRed[0], sRed[1]), fmaxf(sRed[2], sRed[3]));
    float e[4]; float ssum = 0.f;
    #pragma unroll
    for (int i = 0; i < 4; ++i) { e[i] = expf(lv[i] - M); ssum += e[i]; }
    #pragma unroll
    for (int off = 32; off; off >>= 1) ssum += __shfl_down(ssum, off, 64);
    __syncthreads();
    if (lane == 0) sRed[wv] = ssum;
    __syncthreads();
    float inv = 1.0f / (sRed[0] + sRed[1] + sRed[2] + sRed[3]);
    #pragma unroll
    for (int i = 0; i < 4; ++i)
        probs[(size_t)row*SS + tid + i*256] = f2bf(e[i] * inv);
}

// ---------------- Kernel 3: BARRIER-FREE wave-local GEMM, 64Mx32N ----------
// Barrier-based schedules exhausted (plain 187.8 | dbuf 196.9 | BK=256 216.6
// | depth-2 vmcnt 192.4).  This transplants the attn win: wave w's MFMA uses
// A-rows [w*16,w*16+16) (already wave-local) and a PRIVATE per-wave copy of
// the B-tile (4 KB/step, dup'd from L2-resident B) -> ZERO barriers in the
// K-loop.  Each wave free-runs a depth-1 prefetch with per-wave counted
// vmcnt(6) (6 gl16/stage; vmcnt is per-wave so the count is exact).  Hazard:
// parity reuse is 2 steps apart; wave stalls on lgkmcnt at step t's MFMAs
// before issuing step t+1's stage, so reads complete before the overwriting
// write-back arrives (same reasoning as the verified attn loop).  Output
// rows are wave-disjoint -> epilogue barrier-free.  LDS 48 KB -> 3 blk/CU
// = grid depth.  K-order identical -> bit-identical output.
// MODE 0: msgin builder (ctx | hj | ctx*hj, bf16)
// MODE 1: Y1 = bf16(relu(acc + bias))
// MODE 2: out = f32(alpha*(acc + bias))
template<int MODE>
__global__ __launch_bounds__(256) void k_mgemm_nf(
    const unsigned short* __restrict__ A,
    const unsigned short* __restrict__ BT,
    const float* __restrict__ bias,
    const float* __restrict__ Hj,
    const float* __restrict__ alpha_p,
    void* __restrict__ Cout,
    int K, int bt_bstride)
{
    __shared__ __align__(16) unsigned short sA[4][2][16*64];   // 16 KB
    __shared__ __align__(16) unsigned short sB[4][2][32*64];   // 32 KB
    int tid = threadIdx.x;
    int w = tid >> 6, lane = tid & 63;
    int quad = lane >> 4, col = lane & 15;

    // T1 swizzle (measured neutral, kept): each XCD owns contiguous tiles.
    int nwgx = gridDim.x;
    int bid  = blockIdx.y * nwgx + blockIdx.x;
    int q    = (nwgx * gridDim.y) >> 3;            // nwg/8, exact (768/8=96)
    int swz  = (bid & 7) * q + (bid >> 3);
    int n0 = (swz % nwgx) * 32, m0 = (swz / nwgx) * 64;

    int nk = K >> 6;
    const unsigned short* Bb = BT + (size_t)(m0 >> 10) * bt_bstride;

    int srow = lane >> 3;        // 0..7 (8 rows per gl16, 128 B rows)
    int skc  = (lane & 7) * 8;   // element offset within row (16 B per lane)

    floatx4 acc[2];
    acc[0] = (floatx4){0.f,0.f,0.f,0.f};
    acc[1] = (floatx4){0.f,0.f,0.f,0.f};

    // per-wave stage: own A half-tile (2 gl16) + private B copy (4 gl16)
    auto stage = [&](int kb, int p) {
        int kofs = kb*64;
        gl16(A + (size_t)(m0 + w*16     + srow)*K + kofs + skc, &sA[w][p][0]);
        gl16(A + (size_t)(m0 + w*16 + 8 + srow)*K + kofs + skc, &sA[w][p][8*64]);
        #pragma unroll
        for (int i = 0; i < 4; ++i)
            gl16(Bb + (size_t)(n0 + i*8 + srow)*K + kofs + skc, &sB[w][p][i*8*64]);
    };

    stage(0, 0);
    for (int kb = 0; kb < nk; ++kb) {
        int p = kb & 1;
        if (kb + 1 < nk) {
            stage(kb + 1, p ^ 1);                    // depth-1 prefetch
            asm volatile("s_waitcnt vmcnt(6)" ::: "memory");  // tile kb landed
        } else {
            asm volatile("s_waitcnt vmcnt(0)" ::: "memory");
        }
        __builtin_amdgcn_sched_barrier(0);           // no ds_read hoist above
        #pragma unroll
        for (int kt = 0; kt < 2; ++kt) {
            short8 av = *(const short8*)&sA[w][p][col*64 + kt*32 + quad*8];
            #pragma unroll
            for (int nf = 0; nf < 2; ++nf) {
                short8 bv = *(const short8*)&sB[w][p][(nf*16 + col)*64 + kt*32 + quad*8];
                acc[nf] = __builtin_amdgcn_mfma_f32_16x16x32_bf16(av, bv, acc[nf], 0, 0, 0);
            }
        }
        __builtin_amdgcn_sched_barrier(0);           // next stage stays below
    }

    float alpha = (MODE == 2) ? alpha_p[0] : 1.0f;
    #pragma unroll
    for (int nf = 0; nf < 2; ++nf) {
        int n = n0 + nf*16 + col;
        #pragma unroll
        for (int r = 0; r < 4; ++r) {
            int m = w*16 + quad*4 + r;
            size_t g = (size_t)(m0 + m);
            float v = acc[nf][r];
            if (MODE == 0) {
                float hj = Hj[g*HH + n];
                unsigned short* msgin = (unsigned short*)Cout;
                msgin[g*VINN + n]        = f2bf(v);
                msgin[g*VINN + HH + n]   = f2bf(hj);
                msgin[g*VINN + 2*HH + n] = f2bf(v*hj);
            } else if (MODE == 1) {
                ((unsigned short*)Cout)[g*VHIDD + n] =
                    f2bf(fmaxf(v + bias[n], 0.f));
            } else {
                ((float*)Cout)[g*HH + n] = alpha*(v + bias[n]);
            }
        }
    }
}

extern "C" void kernel_launch(void* const* d_in, const int* in_sizes, int n_in,
                              void* d_out, int out_size, void* d_ws, size_t ws_size,
                              hipStream_t stream)
{
    const float* Hj   = (const float*)d_in[0];
    const float* Hi   = (const float*)d_in[1];
    const float* mask = (const float*)d_in[2];
    const float* Wpj  = (const float*)d_in[3];
    const float* Wpi  = (const float*)d_in[4];
    const float* W1   = (const float*)d_in[5];
    const float* b1   = (const float*)d_in[6];
    const float* W2   = (const float*)d_in[7];
    const float* Wv1  = (const float*)d_in[9];
    const float* bv1  = (const float*)d_in[10];
    const float* Wv2  = (const float*)d_in[11];
    const float* bv2  = (const float*)d_in[12];
    const float* alpha = (const float*)d_in[13];
    float* out = (float*)d_out;

    const int NR = NRR;                   // 2048
    char* p = (char*)d_ws;
    auto alloc = [&](size_t bytes) {
        char* r = p; p += (bytes + 255) & ~(size_t)255; return r;
    };
    unsigned* Zjp          = (unsigned*)alloc((size_t)NR*12*4);
    unsigned* Zip          = (unsigned*)alloc((size_t)NR*12*4);
    unsigned short* probsb = (unsigned short*)alloc((size_t)NR*SS*2);
    unsigned short* HiT    = (unsigned short*)alloc((size_t)BB*HH*SS*2);
    unsigned short* Wv1T   = (unsigned short*)alloc((size_t)VHIDD*VINN*2);
    unsigned short* Wv2T   = (unsigned short*)alloc((size_t)HH*VHIDD*2);
    unsigned short* msginb = (unsigned short*)alloc((size_t)NR*VINN*2);
    unsigned short* Y1b    = (unsigned short*)alloc((size_t)NR*VHIDD*2);

    // zproj only: 64 blocks (k_attn depends solely on this)
    k_zproj<<<2*NR/64, 256, 0, stream>>>(Hj, Hi, Wpj, Wpi, Zjp, Zip);

    // attn (2048 blocks) + tconv (3840 blocks) packed in one dispatch:
    // tconv outputs (HiT/Wv1T/Wv2T) are first consumed by the GEMMs below.
    k_attn<<<NR + 1728 + 576 + 1536, 256, 0, stream>>>(
        Zjp, Zip, W1, b1, W2, mask, probsb,
        Hi, Wv1, Wv2, Wv1T, Wv2T, HiT);

    // ctx GEMM: M=2048 (batch via bt stride), N=768, K=1024, no split,
    // fused msgin epilogue. 24 x 32 = 768 blocks.
    k_mgemm_nf<0><<<dim3(HH/32, NR/64), 256, 0, stream>>>(
        probsb, HiT, nullptr, Hj, alpha, msginb, SS, HH*SS);

    // MLP GEMM1: K=2304, no split, fused bias+relu epilogue. 768 blocks.
    k_mgemm_nf<1><<<dim3(VHIDD/32, NR/64), 256, 0, stream>>>(
        msginb, Wv1T, bv1, nullptr, alpha, Y1b, VINN, 0);

    // MLP GEMM2: K=768, no split, fused f32 epilogue. 768 blocks.
    k_mgemm_nf<2><<<dim3(HH/32, NR/64), 256, 0, stream>>>(
        Y1b, Wv2T, bv2, nullptr, alpha, out, VHIDD, 0);
}